// Round 4
// baseline (1190.249 us; speedup 1.0000x reference)
//
#include <hip/hip_runtime.h>

// Problem constants (from reference)
#define NN   100000      // nodes
#define NE   1600000     // edges
#define DD   64          // node feature dim
#define ECH  16          // edge channels
#define EMBD 128
#define G1D  512
#define G2D  64000
#define NGR  100         // graphs
#define NM1D 128

typedef __attribute__((ext_vector_type(8))) short short8;
typedef __attribute__((ext_vector_type(4))) float float4v;

__device__ __forceinline__ float bf2f(unsigned short u) {
    union { unsigned int i; float f; } v; v.i = ((unsigned int)u) << 16; return v.f;
}
__device__ __forceinline__ unsigned short f2bf(float f) {
    union { unsigned int i; float f; } v; v.f = f;
    unsigned int u = v.i;
    return (unsigned short)((u + 0x7fffu + ((u >> 16) & 1u)) >> 16);
}
__device__ __forceinline__ float blo(unsigned int d) {
    union { unsigned int i; float f; } v; v.i = d << 16; return v.f;
}
__device__ __forceinline__ float bhi(unsigned int d) {
    union { unsigned int i; float f; } v; v.i = d & 0xffff0000u; return v.f;
}
__device__ __forceinline__ int iclamp(int v, int lo, int hi) {
    return v < lo ? lo : (v > hi ? hi : v);
}

// ---- dtype-generic accessors (T = float or unsigned short[bf16]) ----
__device__ __forceinline__ float ldf(const float* p, size_t i) { return p[i]; }
__device__ __forceinline__ float ldf(const unsigned short* p, size_t i) { return bf2f(p[i]); }
__device__ __forceinline__ unsigned short ldbf(const float* p, size_t i) { return f2bf(p[i]); }
__device__ __forceinline__ unsigned short ldbf(const unsigned short* p, size_t i) { return p[i]; }
__device__ __forceinline__ void stf(float* p, size_t i, float v) { p[i] = v; }
__device__ __forceinline__ void stf(unsigned short* p, size_t i, float v) { p[i] = f2bf(v); }
__device__ __forceinline__ void ld16v(const float* p, float* o) {
    const float4* q = (const float4*)p;
    float4 a = q[0], b = q[1], c = q[2], d = q[3];
    o[0]=a.x; o[1]=a.y; o[2]=a.z; o[3]=a.w;
    o[4]=b.x; o[5]=b.y; o[6]=b.z; o[7]=b.w;
    o[8]=c.x; o[9]=c.y; o[10]=c.z; o[11]=c.w;
    o[12]=d.x; o[13]=d.y; o[14]=d.z; o[15]=d.w;
}
__device__ __forceinline__ void ld16v(const unsigned short* p, float* o) {
    const uint4* q = (const uint4*)p;
    uint4 a = q[0], b = q[1];
    o[0]=blo(a.x); o[1]=bhi(a.x); o[2]=blo(a.y); o[3]=bhi(a.y);
    o[4]=blo(a.z); o[5]=bhi(a.z); o[6]=blo(a.w); o[7]=bhi(a.w);
    o[8]=blo(b.x); o[9]=bhi(b.x); o[10]=blo(b.y); o[11]=bhi(b.y);
    o[12]=blo(b.z); o[13]=bhi(b.z); o[14]=blo(b.w); o[15]=bhi(b.w);
}
template <typename T> struct tagof;
template <> struct tagof<float> { static constexpr int v = 0; };
template <> struct tagof<unsigned short> { static constexpr int v = 1; };

#define MFMA(a, b, c) __builtin_amdgcn_mfma_f32_16x16x32_bf16((a), (b), (c), 0, 0, 0)

// ---------------- runtime dtype detection ----------------
// dtf[0]: 1 if float tensors are bf16, 0 if fp32.
// dtf[1]: 1 if edge_index stored as int64 words, 0 if int32.
__global__ __launch_bounds__(64) void k_detect(const unsigned short* __restrict__ embu,
                                               const int* __restrict__ eidx,
                                               int* __restrict__ dtf) {
    if (threadIdx.x == 0 && blockIdx.x == 0) {
        int sane = 0;
        for (int i = 0; i < 512; i++) {
            unsigned short x = embu[i];
            int e = (x >> 7) & 0xFF;
            if (x == 0 || (e >= 97 && e <= 157)) sane++;
        }
        dtf[0] = (sane >= 461) ? 1 : 0;
        int allOdd = 1, anyEven = 0;
        for (int i = 0; i < 256; i++) {
            if (eidx[2 * i + 1] != 0) allOdd = 0;
            if (eidx[2 * i] != 0) anyEven = 1;
        }
        dtf[1] = (allOdd && anyEven) ? 1 : 0;
    }
}
__device__ __forceinline__ int ld_src(const int* e, int f, int i) {
    int v = f ? e[2 * i] : e[i];
    return iclamp(v, 0, NN - 1);
}
__device__ __forceinline__ int ld_dst(const int* e, int f, int i) {
    int v = f ? e[2 * (NE + i)] : e[NE + i];
    return iclamp(v, 0, NN - 1);
}

// ---------------- decoder MLP layer 1: h = relu(emb @ Wg1 + bg1) ----------------
template <typename T>
__global__ __launch_bounds__(256) void k_dec1(const int* __restrict__ dtf,
                                              const T* __restrict__ emb,
                                              const T* __restrict__ Wg1,
                                              const T* __restrict__ bg1,
                                              unsigned short* __restrict__ h) {
    if (dtf[0] != tagof<T>::v) return;
    __shared__ float es[EMBD];
    int m = blockIdx.x, t = threadIdx.x;
    if (t < EMBD) es[t] = ldf(emb, (size_t)m * EMBD + t);
    __syncthreads();
    for (int n = t; n < G1D; n += 256) {
        float acc = ldf(bg1, n);
        for (int k = 0; k < EMBD; k++) acc += es[k] * ldf(Wg1, (size_t)k * G1D + n);
        h[m * G1D + n] = f2bf(fmaxf(acc, 0.f));
    }
}

// ---------------- decoder MLP layer 2: x0 = h @ Wg2 + bg2  (MFMA) ----------------
template <typename T>
__global__ __launch_bounds__(256) void k_dec2(const int* __restrict__ dtf,
                                              const unsigned short* __restrict__ h,
                                              const T* __restrict__ Wg2,
                                              const T* __restrict__ bg2,
                                              unsigned short* __restrict__ x) {
    if (dtf[0] != tagof<T>::v) return;
    int wid = threadIdx.x >> 6, lane = threadIdx.x & 63;
    int q = lane >> 4, l16 = lane & 15;
    int n = blockIdx.x * 64 + wid * 16 + l16;
    float4v acc[7];
    for (int mt = 0; mt < 7; mt++) for (int i = 0; i < 4; i++) acc[mt][i] = 0.f;
    for (int kt = 0; kt < 16; kt++) {
        int k0 = kt * 32 + q * 8;
        short8 bf;
        for (int j = 0; j < 8; j++) bf[j] = (short)ldbf(Wg2, (size_t)(k0 + j) * G2D + n);
        for (int mt = 0; mt < 7; mt++) {
            int row = mt * 16 + l16;
            short8 af;
            if (row < NGR) {
                af = *(const short8*)(h + row * G1D + k0);
            } else {
                for (int j = 0; j < 8; j++) af[j] = 0;
            }
            acc[mt] = MFMA(af, bf, acc[mt]);
        }
    }
    float bias = ldf(bg2, n);
    for (int mt = 0; mt < 7; mt++) {
        for (int i = 0; i < 4; i++) {
            int m = mt * 16 + q * 4 + i;
            if (m < NGR) x[(size_t)m * G2D + n] = f2bf(acc[mt][i] + bias);
        }
    }
}

// ---------------- CSR build ----------------
__global__ __launch_bounds__(256) void k_zero(int* __restrict__ deg) {
    int i = blockIdx.x * 256 + threadIdx.x;
    if (i < NN) deg[i] = 0;
}
__global__ __launch_bounds__(256) void k_csrz(int2* __restrict__ csr) {
    int i = blockIdx.x * 256 + threadIdx.x;   // grid exact: NE/256
    csr[i] = make_int2(0, 0);
}
__global__ __launch_bounds__(256) void k_hist(const int* __restrict__ eidx, const int* __restrict__ dtf,
                                              int* __restrict__ deg) {
    int e = blockIdx.x * 256 + threadIdx.x;   // grid exact
    int f = dtf[1];
    atomicAdd(&deg[ld_dst(eidx, f, e)], 1);
}
__global__ __launch_bounds__(256) void k_scan1(const int* __restrict__ deg, int* __restrict__ bsum) {
    __shared__ int r[256];
    int t = threadIdx.x, i0 = blockIdx.x * 512 + 2 * t;
    int e0 = (i0 < NN) ? deg[i0] : 0;
    int e1 = (i0 + 1 < NN) ? deg[i0 + 1] : 0;
    r[t] = e0 + e1;
    __syncthreads();
    for (int off = 128; off > 0; off >>= 1) {
        if (t < off) r[t] += r[t + off];
        __syncthreads();
    }
    if (t == 0) bsum[blockIdx.x] = r[0];
}
__global__ __launch_bounds__(64) void k_scan2(int* __restrict__ bsum, int nblk) {
    if (threadIdx.x == 0) {
        int run = 0;
        for (int b = 0; b < nblk; b++) { int v = bsum[b]; bsum[b] = run; run += v; }
    }
}
__global__ __launch_bounds__(256) void k_scan3(const int* __restrict__ deg, const int* __restrict__ bsum,
                                               int* __restrict__ ptr, int* __restrict__ cur) {
    __shared__ int sc[256];
    int t = threadIdx.x, i0 = blockIdx.x * 512 + 2 * t;
    int e0 = (i0 < NN) ? deg[i0] : 0;
    int e1 = (i0 + 1 < NN) ? deg[i0 + 1] : 0;
    int s = e0 + e1;
    sc[t] = s;
    __syncthreads();
    for (int off = 1; off < 256; off <<= 1) {
        int v = (t >= off) ? sc[t - off] : 0;
        __syncthreads();
        sc[t] += v;
        __syncthreads();
    }
    int excl = sc[t] - s;
    int p0 = bsum[blockIdx.x] + excl;
    if (i0 < NN)     { ptr[i0] = p0;          cur[i0] = p0; }
    if (i0 + 1 < NN) { ptr[i0 + 1] = p0 + e0; cur[i0 + 1] = p0 + e0; }
    if (blockIdx.x == 0 && t == 0) ptr[NN] = NE;
}
__global__ __launch_bounds__(256) void k_fill(const int* __restrict__ eidx, const int* __restrict__ dtf,
                                              int* __restrict__ cur, int2* __restrict__ csr) {
    int e = blockIdx.x * 256 + threadIdx.x;   // grid exact
    int f = dtf[1];
    int src = ld_src(eidx, f, e);
    int dst = ld_dst(eidx, f, e);
    int pos = atomicAdd(&cur[dst], 1);
    pos = iclamp(pos, 0, NE - 1);
    csr[pos] = make_int2(src, e);
}

// ---------------- generic skinny MFMA GEMM over node rows ----------------
template <typename T, int KT1, int KT2, int NT, bool RELU, bool HASBIAS>
__global__ __launch_bounds__(256) void gemm_node(const int* __restrict__ dtf,
                                                 const unsigned short* __restrict__ A1,
                                                 const unsigned short* __restrict__ A2,
                                                 const T* __restrict__ W,
                                                 const T* __restrict__ bias,
                                                 unsigned short* __restrict__ out) {
    if (dtf[0] != tagof<T>::v) return;
    constexpr int KT = KT1 + KT2;
    constexpr int N = NT * 16;
    int wid = threadIdx.x >> 6, lane = threadIdx.x & 63;
    int q = lane >> 4, l16 = lane & 15;
    int mt = blockIdx.x * 4 + wid;
    int m0 = mt * 16;
    if (m0 >= NN) return;
    short8 bfr[KT][NT];
    for (int kt = 0; kt < KT; kt++)
        for (int nt = 0; nt < NT; nt++)
            for (int j = 0; j < 8; j++)
                bfr[kt][nt][j] = (short)ldbf(W, (size_t)(kt * 32 + q * 8 + j) * N + nt * 16 + l16);
    float4v acc[NT];
    for (int nt = 0; nt < NT; nt++) for (int i = 0; i < 4; i++) acc[nt][i] = 0.f;

    const unsigned short* a1p = A1 + (size_t)(m0 + l16) * (KT1 * 32) + q * 8;
    for (int kt = 0; kt < KT1; kt++) {
        short8 af = *(const short8*)(a1p + kt * 32);
        for (int nt = 0; nt < NT; nt++) acc[nt] = MFMA(af, bfr[kt][nt], acc[nt]);
    }
    if constexpr (KT2 > 0) {
        const unsigned short* a2p = A2 + (size_t)(m0 + l16) * (KT2 * 32) + q * 8;
        for (int kt = 0; kt < KT2; kt++) {
            short8 af = *(const short8*)(a2p + kt * 32);
            for (int nt = 0; nt < NT; nt++) acc[nt] = MFMA(af, bfr[KT1 + kt][nt], acc[nt]);
        }
    }
    for (int nt = 0; nt < NT; nt++) {
        int n = nt * 16 + l16;
        float b = HASBIAS ? ldf(bias, n) : 0.f;
        for (int i = 0; i < 4; i++) {
            float v = acc[nt][i] + b;
            if (RELU) v = fmaxf(v, 0.f);
            out[(size_t)(m0 + q * 4 + i) * N + n] = f2bf(v);
        }
    }
}

// ---------------- edge aggregation: agg[d] = sum_in-edges relu(y[src] + e@We + mb) ----------------
template <typename T>
__global__ __launch_bounds__(256) void k_agg(const int* __restrict__ dtf,
                                             const int2* __restrict__ csr, const int* __restrict__ ptr,
                                             const unsigned short* __restrict__ y,
                                             const T* __restrict__ ea,
                                             const T* __restrict__ mW,
                                             const T* __restrict__ mb,
                                             unsigned short* __restrict__ agg) {
    if (dtf[0] != tagof<T>::v) return;
    int nid = blockIdx.x * 4 + (threadIdx.x >> 6);
    int lane = threadIdx.x & 63;
    float wk[16];
    for (int k = 0; k < 16; k++) wk[k] = ldf(mW, (size_t)(DD + k) * DD + lane);
    float mbv = ldf(mb, lane);
    int s = iclamp(ptr[nid], 0, NE);
    int e = iclamp(ptr[nid + 1], s, NE);
    float acc = 0.f;
    for (int t = s; t < e; ++t) {
        int2 p = csr[t];
        int sidx = iclamp(p.x, 0, NN - 1);
        int eid  = iclamp(p.y, 0, NE - 1);
        float z = mbv + bf2f(y[(size_t)sidx * DD + lane]);
        float ev[16];
        ld16v(ea + (size_t)eid * ECH, ev);
        #pragma unroll
        for (int k = 0; k < 16; k++) z = fmaf(ev[k], wk[k], z);
        acc += fmaxf(z, 0.f);
    }
    agg[(size_t)nid * DD + lane] = f2bf(acc);
}

// ---------------- fused node MLP: out = relu(x @ nW1 + nb1) @ nW2 + nb2 ----------------
template <typename T>
__global__ __launch_bounds__(256) void k_mlp_out(const int* __restrict__ dtf,
                                                 const unsigned short* __restrict__ A,
                                                 const T* __restrict__ nW1,
                                                 const T* __restrict__ nb1,
                                                 const T* __restrict__ nW2,
                                                 const T* __restrict__ nb2,
                                                 T* __restrict__ out) {
    if (dtf[0] != tagof<T>::v) return;
    constexpr int NT = 8, N = 128;
    int wid = threadIdx.x >> 6, lane = threadIdx.x & 63;
    int q = lane >> 4, l16 = lane & 15;
    int mt = blockIdx.x * 4 + wid;
    int m0 = mt * 16;
    if (m0 >= NN) return;
    short8 bfr[2][NT];
    float cb[NT], w2r[NT][3];
    for (int kt = 0; kt < 2; kt++)
        for (int nt = 0; nt < NT; nt++)
            for (int j = 0; j < 8; j++)
                bfr[kt][nt][j] = (short)ldbf(nW1, (size_t)(kt * 32 + q * 8 + j) * N + nt * 16 + l16);
    for (int nt = 0; nt < NT; nt++) {
        int col = nt * 16 + l16;
        cb[nt] = ldf(nb1, col);
        for (int j = 0; j < 3; j++) w2r[nt][j] = ldf(nW2, (size_t)col * 3 + j);
    }
    float4v acc[NT];
    for (int nt = 0; nt < NT; nt++) for (int i = 0; i < 4; i++) acc[nt][i] = 0.f;
    const unsigned short* ap = A + (size_t)(m0 + l16) * DD + q * 8;
    for (int kt = 0; kt < 2; kt++) {
        short8 af = *(const short8*)(ap + kt * 32);
        for (int nt = 0; nt < NT; nt++) acc[nt] = MFMA(af, bfr[kt][nt], acc[nt]);
    }
    float b0 = ldf(nb2, 0), b1 = ldf(nb2, 1), b2 = ldf(nb2, 2);
    for (int i = 0; i < 4; i++) {
        float p0 = 0.f, p1 = 0.f, p2 = 0.f;
        for (int nt = 0; nt < NT; nt++) {
            float v = fmaxf(acc[nt][i] + cb[nt], 0.f);
            p0 += v * w2r[nt][0];
            p1 += v * w2r[nt][1];
            p2 += v * w2r[nt][2];
        }
        for (int m = 1; m < 16; m <<= 1) {
            p0 += __shfl_xor(p0, m);
            p1 += __shfl_xor(p1, m);
            p2 += __shfl_xor(p2, m);
        }
        if (l16 == 0) {
            size_t row = (size_t)(m0 + q * 4 + i) * 3;
            stf(out, row + 0, p0 + b0);
            stf(out, row + 1, p1 + b1);
            stf(out, row + 2, p2 + b2);
        }
    }
}

// ---------------- typed pipeline launcher (no macro: commas in <<<>>> are fine here) ----------------
template <typename T>
static void launch_typed(void* const* d_in, void* d_out, hipStream_t stream,
                         const int* dtf, const int2* csr, const int* ptr,
                         unsigned short* nA, unsigned short* nB, unsigned short* nG,
                         unsigned short* hb, int GEMM_BLKS) {
    const T* emb = (const T*)d_in[0];
    const T* ea  = (const T*)d_in[2];
    const T* Wg1 = (const T*)d_in[3];  const T* bg1 = (const T*)d_in[4];
    const T* Wg2 = (const T*)d_in[5];  const T* bg2 = (const T*)d_in[6];
    const T* mW0 = (const T*)d_in[7];  const T* mb0 = (const T*)d_in[8];
    const T* uW0 = (const T*)d_in[9];  const T* ub0 = (const T*)d_in[10];
    const T* mW1 = (const T*)d_in[11]; const T* mb1 = (const T*)d_in[12];
    const T* uW1 = (const T*)d_in[13]; const T* ub1 = (const T*)d_in[14];
    const T* nW1 = (const T*)d_in[15]; const T* nb1 = (const T*)d_in[16];
    const T* nW2 = (const T*)d_in[17]; const T* nb2 = (const T*)d_in[18];
    T* out = (T*)d_out;

    k_dec1<T><<<NGR, 256, 0, stream>>>(dtf, emb, Wg1, bg1, hb);
    k_dec2<T><<<G2D / 64, 256, 0, stream>>>(dtf, hb, Wg2, bg2, nA);

    gemm_node<T, 2, 0, 4, false, false><<<GEMM_BLKS, 256, 0, stream>>>(dtf, nA, nullptr, mW0, nullptr, nB);
    k_agg<T><<<NN / 4, 256, 0, stream>>>(dtf, csr, ptr, nB, ea, mW0, mb0, nG);
    gemm_node<T, 2, 2, 4, true, true><<<GEMM_BLKS, 256, 0, stream>>>(dtf, nA, nG, uW0, ub0, nB);

    gemm_node<T, 2, 0, 4, false, false><<<GEMM_BLKS, 256, 0, stream>>>(dtf, nB, nullptr, mW1, nullptr, nA);
    k_agg<T><<<NN / 4, 256, 0, stream>>>(dtf, csr, ptr, nA, ea, mW1, mb1, nG);
    gemm_node<T, 2, 2, 4, true, true><<<GEMM_BLKS, 256, 0, stream>>>(dtf, nB, nG, uW1, ub1, nA);

    k_mlp_out<T><<<GEMM_BLKS, 256, 0, stream>>>(dtf, nA, nW1, nb1, nW2, nb2, out);
}

extern "C" void kernel_launch(void* const* d_in, const int* in_sizes, int n_in,
                              void* d_out, int out_size, void* d_ws, size_t ws_size,
                              hipStream_t stream) {
    const int* eix = (const int*)d_in[1];

    // workspace carve-up (~52.3 MB total)
    char* w = (char*)d_ws;
    size_t off = 0;
    auto carve = [&](size_t bytes) { char* p = w + off; off = (off + bytes + 255) & ~(size_t)255; return p; };
    unsigned short* nA = (unsigned short*)carve((size_t)NN * DD * 2);   // 12.8 MB
    unsigned short* nB = (unsigned short*)carve((size_t)NN * DD * 2);   // 12.8 MB
    unsigned short* nG = (unsigned short*)carve((size_t)NN * DD * 2);   // 12.8 MB
    int2* csr = (int2*)carve((size_t)NE * 8);                           // 12.8 MB
    unsigned short* hb = (unsigned short*)carve((size_t)NGR * G1D * 2); // 0.1 MB
    int* deg  = (int*)carve((size_t)NN * 4);
    int* ptr  = (int*)carve((size_t)(NN + 1) * 4);
    int* cur  = (int*)carve((size_t)NN * 4);
    int* bsum = (int*)carve((size_t)256 * 4);
    int* dtf  = (int*)carve(256);
    (void)ws_size; (void)in_sizes; (void)n_in; (void)out_size;

    const int SCAN_BLKS = (NN + 511) / 512;   // 196
    const int GEMM_BLKS = (NN / 16 + 3) / 4;  // 1563

    k_detect<<<1, 64, 0, stream>>>((const unsigned short*)d_in[0], eix, dtf);

    // CSR build (dtype-independent)
    k_zero<<<(NN + 255) / 256, 256, 0, stream>>>(deg);
    k_csrz<<<NE / 256, 256, 0, stream>>>(csr);
    k_hist<<<NE / 256, 256, 0, stream>>>(eix, dtf, deg);
    k_scan1<<<SCAN_BLKS, 256, 0, stream>>>(deg, bsum);
    k_scan2<<<1, 64, 0, stream>>>(bsum, SCAN_BLKS);
    k_scan3<<<SCAN_BLKS, 256, 0, stream>>>(deg, bsum, ptr, cur);
    k_fill<<<NE / 256, 256, 0, stream>>>(eix, dtf, cur, csr);

    // launch both dtype variants; the wrong one early-exits on dtf[0]
    launch_typed<float>(d_in, d_out, stream, dtf, csr, ptr, nA, nB, nG, hb, GEMM_BLKS);
    launch_typed<unsigned short>(d_in, d_out, stream, dtf, csr, ptr, nA, nB, nG, hb, GEMM_BLKS);
}

// Round 5
// 1002.147 us; speedup vs baseline: 1.1877x; 1.1877x over previous
//
#include <hip/hip_runtime.h>

// Problem constants (from reference)
#define NN   100000      // nodes
#define NE   1600000     // edges
#define DD   64          // node feature dim
#define ECH  16          // edge channels
#define EMBD 128
#define G1D  512
#define G2D  64000
#define NGR  100         // graphs
#define NM1D 128

typedef __attribute__((ext_vector_type(8))) short short8;
typedef __attribute__((ext_vector_type(4))) float float4v;

__device__ __forceinline__ float bf2f(unsigned short u) {
    union { unsigned int i; float f; } v; v.i = ((unsigned int)u) << 16; return v.f;
}
__device__ __forceinline__ unsigned short f2bf(float f) {
    union { unsigned int i; float f; } v; v.f = f;
    unsigned int u = v.i;
    return (unsigned short)((u + 0x7fffu + ((u >> 16) & 1u)) >> 16);
}
__device__ __forceinline__ float blo(unsigned int d) {
    union { unsigned int i; float f; } v; v.i = d << 16; return v.f;
}
__device__ __forceinline__ float bhi(unsigned int d) {
    union { unsigned int i; float f; } v; v.i = d & 0xffff0000u; return v.f;
}
__device__ __forceinline__ int iclamp(int v, int lo, int hi) {
    return v < lo ? lo : (v > hi ? hi : v);
}

// ---- dtype-generic accessors (T = float or unsigned short[bf16]) ----
__device__ __forceinline__ float ldf(const float* p, size_t i) { return p[i]; }
__device__ __forceinline__ float ldf(const unsigned short* p, size_t i) { return bf2f(p[i]); }
__device__ __forceinline__ unsigned short ldbf(const float* p, size_t i) { return f2bf(p[i]); }
__device__ __forceinline__ unsigned short ldbf(const unsigned short* p, size_t i) { return p[i]; }
__device__ __forceinline__ void stf(float* p, size_t i, float v) { p[i] = v; }
__device__ __forceinline__ void stf(unsigned short* p, size_t i, float v) { p[i] = f2bf(v); }
__device__ __forceinline__ void ld16v(const float* p, float* o) {
    const float4* q = (const float4*)p;
    float4 a = q[0], b = q[1], c = q[2], d = q[3];
    o[0]=a.x; o[1]=a.y; o[2]=a.z; o[3]=a.w;
    o[4]=b.x; o[5]=b.y; o[6]=b.z; o[7]=b.w;
    o[8]=c.x; o[9]=c.y; o[10]=c.z; o[11]=c.w;
    o[12]=d.x; o[13]=d.y; o[14]=d.z; o[15]=d.w;
}
__device__ __forceinline__ void ld16v(const unsigned short* p, float* o) {
    const uint4* q = (const uint4*)p;
    uint4 a = q[0], b = q[1];
    o[0]=blo(a.x); o[1]=bhi(a.x); o[2]=blo(a.y); o[3]=bhi(a.y);
    o[4]=blo(a.z); o[5]=bhi(a.z); o[6]=blo(a.w); o[7]=bhi(a.w);
    o[8]=blo(b.x); o[9]=bhi(b.x); o[10]=blo(b.y); o[11]=bhi(b.y);
    o[12]=blo(b.z); o[13]=bhi(b.z); o[14]=blo(b.w); o[15]=bhi(b.w);
}
template <typename T> struct tagof;
template <> struct tagof<float> { static constexpr int v = 0; };
template <> struct tagof<unsigned short> { static constexpr int v = 1; };

#define MFMA(a, b, c) __builtin_amdgcn_mfma_f32_16x16x32_bf16((a), (b), (c), 0, 0, 0)

// ---------------- runtime dtype detection (parallel, 1 wave) ----------------
// dtf[0]: 1 if float tensors are bf16, 0 if fp32.
// dtf[1]: 1 if edge_index stored as int64 words, 0 if int32.
__global__ __launch_bounds__(64) void k_detect(const unsigned short* __restrict__ embu,
                                               const int* __restrict__ eidx,
                                               int* __restrict__ dtf) {
    int lane = threadIdx.x;
    int sane = 0;
    for (int i = lane; i < 512; i += 64) {
        unsigned short x = embu[i];
        int e = (x >> 7) & 0xFF;
        if (x == 0 || (e >= 97 && e <= 157)) sane++;
    }
    for (int m = 32; m >= 1; m >>= 1) sane += __shfl_xor(sane, m);
    int oddNZ = 0, evenNZ = 0;
    for (int i = lane; i < 256; i += 64) {
        if (eidx[2 * i + 1] != 0) oddNZ = 1;
        if (eidx[2 * i] != 0) evenNZ = 1;
    }
    unsigned long long bo = __ballot(oddNZ);
    unsigned long long be = __ballot(evenNZ);
    if (lane == 0) {
        dtf[0] = (sane >= 461) ? 1 : 0;
        dtf[1] = (bo == 0ULL && be != 0ULL) ? 1 : 0;
    }
}
__device__ __forceinline__ int ld_src(const int* e, int f, int i) {
    int v = f ? e[2 * i] : e[i];
    return iclamp(v, 0, NN - 1);
}
__device__ __forceinline__ int ld_dst(const int* e, int f, int i) {
    int v = f ? e[2 * (NE + i)] : e[NE + i];
    return iclamp(v, 0, NN - 1);
}

// ---------------- decoder MLP layer 1: h = relu(emb @ Wg1 + bg1) ----------------
template <typename T>
__global__ __launch_bounds__(256) void k_dec1(const int* __restrict__ dtf,
                                              const T* __restrict__ emb,
                                              const T* __restrict__ Wg1,
                                              const T* __restrict__ bg1,
                                              unsigned short* __restrict__ h) {
    if (dtf[0] != tagof<T>::v) return;
    __shared__ float es[EMBD];
    int m = blockIdx.x, t = threadIdx.x;
    if (t < EMBD) es[t] = ldf(emb, (size_t)m * EMBD + t);
    __syncthreads();
    for (int n = t; n < G1D; n += 256) {
        float acc = ldf(bg1, n);
        for (int k = 0; k < EMBD; k++) acc += es[k] * ldf(Wg1, (size_t)k * G1D + n);
        h[m * G1D + n] = f2bf(fmaxf(acc, 0.f));
    }
}

// ---------------- decoder MLP layer 2: x0 = h @ Wg2 + bg2  (MFMA) ----------------
template <typename T>
__global__ __launch_bounds__(256) void k_dec2(const int* __restrict__ dtf,
                                              const unsigned short* __restrict__ h,
                                              const T* __restrict__ Wg2,
                                              const T* __restrict__ bg2,
                                              unsigned short* __restrict__ x) {
    if (dtf[0] != tagof<T>::v) return;
    int wid = threadIdx.x >> 6, lane = threadIdx.x & 63;
    int q = lane >> 4, l16 = lane & 15;
    int n = blockIdx.x * 64 + wid * 16 + l16;
    float4v acc[7];
    for (int mt = 0; mt < 7; mt++) for (int i = 0; i < 4; i++) acc[mt][i] = 0.f;
    for (int kt = 0; kt < 16; kt++) {
        int k0 = kt * 32 + q * 8;
        short8 bf;
        for (int j = 0; j < 8; j++) bf[j] = (short)ldbf(Wg2, (size_t)(k0 + j) * G2D + n);
        for (int mt = 0; mt < 7; mt++) {
            int row = mt * 16 + l16;
            short8 af;
            if (row < NGR) {
                af = *(const short8*)(h + row * G1D + k0);
            } else {
                for (int j = 0; j < 8; j++) af[j] = 0;
            }
            acc[mt] = MFMA(af, bf, acc[mt]);
        }
    }
    float bias = ldf(bg2, n);
    for (int mt = 0; mt < 7; mt++) {
        for (int i = 0; i < 4; i++) {
            int m = mt * 16 + q * 4 + i;
            if (m < NGR) x[(size_t)m * G2D + n] = f2bf(acc[mt][i] + bias);
        }
    }
}

// ---------------- CSR build ----------------
__global__ __launch_bounds__(256) void k_zero(int* __restrict__ deg) {
    int i = blockIdx.x * 256 + threadIdx.x;
    if (i < NN) deg[i] = 0;
}
__global__ __launch_bounds__(256) void k_hist(const int* __restrict__ eidx, const int* __restrict__ dtf,
                                              int* __restrict__ deg) {
    int e = blockIdx.x * 256 + threadIdx.x;   // grid exact
    int f = dtf[1];
    atomicAdd(&deg[ld_dst(eidx, f, e)], 1);
}
__global__ __launch_bounds__(256) void k_scan1(const int* __restrict__ deg, int* __restrict__ bsum) {
    __shared__ int r[256];
    int t = threadIdx.x, i0 = blockIdx.x * 512 + 2 * t;
    int e0 = (i0 < NN) ? deg[i0] : 0;
    int e1 = (i0 + 1 < NN) ? deg[i0 + 1] : 0;
    r[t] = e0 + e1;
    __syncthreads();
    for (int off = 128; off > 0; off >>= 1) {
        if (t < off) r[t] += r[t + off];
        __syncthreads();
    }
    if (t == 0) bsum[blockIdx.x] = r[0];
}
// one-block parallel exclusive scan over nblk (<=256) block sums
__global__ __launch_bounds__(256) void k_scan2(int* __restrict__ bsum, int nblk) {
    __shared__ int sc[256];
    int t = threadIdx.x;
    int v = (t < nblk) ? bsum[t] : 0;
    sc[t] = v;
    __syncthreads();
    for (int off = 1; off < 256; off <<= 1) {
        int u = (t >= off) ? sc[t - off] : 0;
        __syncthreads();
        sc[t] += u;
        __syncthreads();
    }
    if (t < nblk) bsum[t] = sc[t] - v;   // exclusive
}
__global__ __launch_bounds__(256) void k_scan3(const int* __restrict__ deg, const int* __restrict__ bsum,
                                               int* __restrict__ ptr, int* __restrict__ cur) {
    __shared__ int sc[256];
    int t = threadIdx.x, i0 = blockIdx.x * 512 + 2 * t;
    int e0 = (i0 < NN) ? deg[i0] : 0;
    int e1 = (i0 + 1 < NN) ? deg[i0 + 1] : 0;
    int s = e0 + e1;
    sc[t] = s;
    __syncthreads();
    for (int off = 1; off < 256; off <<= 1) {
        int v = (t >= off) ? sc[t - off] : 0;
        __syncthreads();
        sc[t] += v;
        __syncthreads();
    }
    int excl = sc[t] - s;
    int p0 = bsum[blockIdx.x] + excl;
    if (i0 < NN)     { ptr[i0] = p0;          cur[i0] = p0; }
    if (i0 + 1 < NN) { ptr[i0 + 1] = p0 + e0; cur[i0 + 1] = p0 + e0; }
    if (blockIdx.x == 0 && t == 0) ptr[NN] = NE;
}
__global__ __launch_bounds__(256) void k_fill(const int* __restrict__ eidx, const int* __restrict__ dtf,
                                              int* __restrict__ cur, int2* __restrict__ csr) {
    int e = blockIdx.x * 256 + threadIdx.x;   // grid exact
    int f = dtf[1];
    int src = ld_src(eidx, f, e);
    int dst = ld_dst(eidx, f, e);
    int pos = atomicAdd(&cur[dst], 1);
    pos = iclamp(pos, 0, NE - 1);
    csr[pos] = make_int2(src, e);
}

// ---------------- permute edge_attr into CSR order (bf16-packed) ----------------
template <typename T>
__global__ __launch_bounds__(256) void k_eaperm(const int* __restrict__ dtf,
                                                const int2* __restrict__ csr,
                                                const T* __restrict__ ea,
                                                unsigned short* __restrict__ eaP) {
    if (dtf[0] != tagof<T>::v) return;
    int p = blockIdx.x * 256 + threadIdx.x;   // grid exact: NE/256
    int eid = iclamp(csr[p].y, 0, NE - 1);
    float ev[16];
    ld16v(ea + (size_t)eid * ECH, ev);
    unsigned int wv[8];
    for (int i = 0; i < 8; i++)
        wv[i] = (unsigned int)f2bf(ev[2 * i]) | ((unsigned int)f2bf(ev[2 * i + 1]) << 16);
    uint4* op = (uint4*)(eaP + (size_t)p * ECH);
    op[0] = make_uint4(wv[0], wv[1], wv[2], wv[3]);
    op[1] = make_uint4(wv[4], wv[5], wv[6], wv[7]);
}

// ---------------- edge aggregation ----------------
__device__ __forceinline__ float edge_val(float yv, uint4 a, uint4 b, const float* wk, float mbv) {
    float z = mbv + yv;
    z = fmaf(blo(a.x), wk[0], z);  z = fmaf(bhi(a.x), wk[1], z);
    z = fmaf(blo(a.y), wk[2], z);  z = fmaf(bhi(a.y), wk[3], z);
    z = fmaf(blo(a.z), wk[4], z);  z = fmaf(bhi(a.z), wk[5], z);
    z = fmaf(blo(a.w), wk[6], z);  z = fmaf(bhi(a.w), wk[7], z);
    z = fmaf(blo(b.x), wk[8], z);  z = fmaf(bhi(b.x), wk[9], z);
    z = fmaf(blo(b.y), wk[10], z); z = fmaf(bhi(b.y), wk[11], z);
    z = fmaf(blo(b.z), wk[12], z); z = fmaf(bhi(b.z), wk[13], z);
    z = fmaf(blo(b.w), wk[14], z); z = fmaf(bhi(b.w), wk[15], z);
    return fmaxf(z, 0.f);
}

// PERM=true: ea pre-permuted into eaP (bf16, CSR order, sequential reads).
template <typename T, bool PERM>
__global__ __launch_bounds__(256) void k_agg(const int* __restrict__ dtf,
                                             const int2* __restrict__ csr, const int* __restrict__ ptr,
                                             const unsigned short* __restrict__ y,
                                             const T* __restrict__ ea,
                                             const unsigned short* __restrict__ eaP,
                                             const T* __restrict__ mW,
                                             const T* __restrict__ mb,
                                             unsigned short* __restrict__ agg) {
    if (dtf[0] != tagof<T>::v) return;
    int nid = blockIdx.x * 4 + (threadIdx.x >> 6);
    int lane = threadIdx.x & 63;
    float wk[16];
    for (int k = 0; k < 16; k++) wk[k] = ldf(mW, (size_t)(DD + k) * DD + lane);
    float mbv = ldf(mb, lane);
    int s = iclamp(ptr[nid], 0, NE);
    int e = iclamp(ptr[nid + 1], s, NE);
    float acc = 0.f;
    int t = s;
    if constexpr (PERM) {
        for (; t + 4 <= e; t += 4) {
            int2 c0 = csr[t], c1 = csr[t + 1], c2 = csr[t + 2], c3 = csr[t + 3];
            float y0 = bf2f(y[(size_t)iclamp(c0.x, 0, NN - 1) * DD + lane]);
            float y1 = bf2f(y[(size_t)iclamp(c1.x, 0, NN - 1) * DD + lane]);
            float y2 = bf2f(y[(size_t)iclamp(c2.x, 0, NN - 1) * DD + lane]);
            float y3 = bf2f(y[(size_t)iclamp(c3.x, 0, NN - 1) * DD + lane]);
            const uint4* ep = (const uint4*)(eaP + (size_t)t * ECH);
            uint4 a0 = ep[0], b0 = ep[1], a1 = ep[2], b1 = ep[3];
            uint4 a2 = ep[4], b2 = ep[5], a3 = ep[6], b3 = ep[7];
            acc += edge_val(y0, a0, b0, wk, mbv);
            acc += edge_val(y1, a1, b1, wk, mbv);
            acc += edge_val(y2, a2, b2, wk, mbv);
            acc += edge_val(y3, a3, b3, wk, mbv);
        }
        for (; t < e; ++t) {
            int2 p = csr[t];
            float yv = bf2f(y[(size_t)iclamp(p.x, 0, NN - 1) * DD + lane]);
            const uint4* ep = (const uint4*)(eaP + (size_t)t * ECH);
            acc += edge_val(yv, ep[0], ep[1], wk, mbv);
        }
    } else {
        for (; t + 2 <= e; t += 2) {
            int2 p0 = csr[t], p1 = csr[t + 1];
            float y0 = bf2f(y[(size_t)iclamp(p0.x, 0, NN - 1) * DD + lane]);
            float y1 = bf2f(y[(size_t)iclamp(p1.x, 0, NN - 1) * DD + lane]);
            float e0[16], e1[16];
            ld16v(ea + (size_t)iclamp(p0.y, 0, NE - 1) * ECH, e0);
            ld16v(ea + (size_t)iclamp(p1.y, 0, NE - 1) * ECH, e1);
            float z0 = mbv + y0, z1 = mbv + y1;
            #pragma unroll
            for (int k = 0; k < 16; k++) { z0 = fmaf(e0[k], wk[k], z0); z1 = fmaf(e1[k], wk[k], z1); }
            acc += fmaxf(z0, 0.f) + fmaxf(z1, 0.f);
        }
        for (; t < e; ++t) {
            int2 p = csr[t];
            float yv = bf2f(y[(size_t)iclamp(p.x, 0, NN - 1) * DD + lane]);
            float ev[16];
            ld16v(ea + (size_t)iclamp(p.y, 0, NE - 1) * ECH, ev);
            float z = mbv + yv;
            #pragma unroll
            for (int k = 0; k < 16; k++) z = fmaf(ev[k], wk[k], z);
            acc += fmaxf(z, 0.f);
        }
    }
    agg[(size_t)nid * DD + lane] = f2bf(acc);
}

// ---------------- generic skinny MFMA GEMM over node rows ----------------
template <typename T, int KT1, int KT2, int NT, bool RELU, bool HASBIAS>
__global__ __launch_bounds__(256) void gemm_node(const int* __restrict__ dtf,
                                                 const unsigned short* __restrict__ A1,
                                                 const unsigned short* __restrict__ A2,
                                                 const T* __restrict__ W,
                                                 const T* __restrict__ bias,
                                                 unsigned short* __restrict__ out) {
    if (dtf[0] != tagof<T>::v) return;
    constexpr int KT = KT1 + KT2;
    constexpr int N = NT * 16;
    int wid = threadIdx.x >> 6, lane = threadIdx.x & 63;
    int q = lane >> 4, l16 = lane & 15;
    int mt = blockIdx.x * 4 + wid;
    int m0 = mt * 16;
    if (m0 >= NN) return;
    short8 bfr[KT][NT];
    for (int kt = 0; kt < KT; kt++)
        for (int nt = 0; nt < NT; nt++)
            for (int j = 0; j < 8; j++)
                bfr[kt][nt][j] = (short)ldbf(W, (size_t)(kt * 32 + q * 8 + j) * N + nt * 16 + l16);
    float4v acc[NT];
    for (int nt = 0; nt < NT; nt++) for (int i = 0; i < 4; i++) acc[nt][i] = 0.f;

    const unsigned short* a1p = A1 + (size_t)(m0 + l16) * (KT1 * 32) + q * 8;
    for (int kt = 0; kt < KT1; kt++) {
        short8 af = *(const short8*)(a1p + kt * 32);
        for (int nt = 0; nt < NT; nt++) acc[nt] = MFMA(af, bfr[kt][nt], acc[nt]);
    }
    if constexpr (KT2 > 0) {
        const unsigned short* a2p = A2 + (size_t)(m0 + l16) * (KT2 * 32) + q * 8;
        for (int kt = 0; kt < KT2; kt++) {
            short8 af = *(const short8*)(a2p + kt * 32);
            for (int nt = 0; nt < NT; nt++) acc[nt] = MFMA(af, bfr[KT1 + kt][nt], acc[nt]);
        }
    }
    for (int nt = 0; nt < NT; nt++) {
        int n = nt * 16 + l16;
        float b = HASBIAS ? ldf(bias, n) : 0.f;
        for (int i = 0; i < 4; i++) {
            float v = acc[nt][i] + b;
            if (RELU) v = fmaxf(v, 0.f);
            out[(size_t)(m0 + q * 4 + i) * N + n] = f2bf(v);
        }
    }
}

// ---------------- fused node MLP: out = relu(x @ nW1 + nb1) @ nW2 + nb2 ----------------
template <typename T>
__global__ __launch_bounds__(256) void k_mlp_out(const int* __restrict__ dtf,
                                                 const unsigned short* __restrict__ A,
                                                 const T* __restrict__ nW1,
                                                 const T* __restrict__ nb1,
                                                 const T* __restrict__ nW2,
                                                 const T* __restrict__ nb2,
                                                 T* __restrict__ out) {
    if (dtf[0] != tagof<T>::v) return;
    constexpr int NT = 8, N = 128;
    int wid = threadIdx.x >> 6, lane = threadIdx.x & 63;
    int q = lane >> 4, l16 = lane & 15;
    int mt = blockIdx.x * 4 + wid;
    int m0 = mt * 16;
    if (m0 >= NN) return;
    short8 bfr[2][NT];
    float cb[NT], w2r[NT][3];
    for (int kt = 0; kt < 2; kt++)
        for (int nt = 0; nt < NT; nt++)
            for (int j = 0; j < 8; j++)
                bfr[kt][nt][j] = (short)ldbf(nW1, (size_t)(kt * 32 + q * 8 + j) * N + nt * 16 + l16);
    for (int nt = 0; nt < NT; nt++) {
        int col = nt * 16 + l16;
        cb[nt] = ldf(nb1, col);
        for (int j = 0; j < 3; j++) w2r[nt][j] = ldf(nW2, (size_t)col * 3 + j);
    }
    float4v acc[NT];
    for (int nt = 0; nt < NT; nt++) for (int i = 0; i < 4; i++) acc[nt][i] = 0.f;
    const unsigned short* ap = A + (size_t)(m0 + l16) * DD + q * 8;
    for (int kt = 0; kt < 2; kt++) {
        short8 af = *(const short8*)(ap + kt * 32);
        for (int nt = 0; nt < NT; nt++) acc[nt] = MFMA(af, bfr[kt][nt], acc[nt]);
    }
    float b0 = ldf(nb2, 0), b1 = ldf(nb2, 1), b2 = ldf(nb2, 2);
    for (int i = 0; i < 4; i++) {
        float p0 = 0.f, p1 = 0.f, p2 = 0.f;
        for (int nt = 0; nt < NT; nt++) {
            float v = fmaxf(acc[nt][i] + cb[nt], 0.f);
            p0 += v * w2r[nt][0];
            p1 += v * w2r[nt][1];
            p2 += v * w2r[nt][2];
        }
        for (int m = 1; m < 16; m <<= 1) {
            p0 += __shfl_xor(p0, m);
            p1 += __shfl_xor(p1, m);
            p2 += __shfl_xor(p2, m);
        }
        if (l16 == 0) {
            size_t row = (size_t)(m0 + q * 4 + i) * 3;
            stf(out, row + 0, p0 + b0);
            stf(out, row + 1, p1 + b1);
            stf(out, row + 2, p2 + b2);
        }
    }
}

// ---------------- typed pipeline launcher ----------------
template <typename T, bool PERM>
static void launch_typed(void* const* d_in, void* d_out, hipStream_t stream,
                         const int* dtf, const int2* csr, const int* ptr,
                         const unsigned short* eaP,
                         unsigned short* nA, unsigned short* nB, unsigned short* nG,
                         unsigned short* hb, int GEMM_BLKS) {
    const T* emb = (const T*)d_in[0];
    const T* ea  = (const T*)d_in[2];
    const T* Wg1 = (const T*)d_in[3];  const T* bg1 = (const T*)d_in[4];
    const T* Wg2 = (const T*)d_in[5];  const T* bg2 = (const T*)d_in[6];
    const T* mW0 = (const T*)d_in[7];  const T* mb0 = (const T*)d_in[8];
    const T* uW0 = (const T*)d_in[9];  const T* ub0 = (const T*)d_in[10];
    const T* mW1 = (const T*)d_in[11]; const T* mb1 = (const T*)d_in[12];
    const T* uW1 = (const T*)d_in[13]; const T* ub1 = (const T*)d_in[14];
    const T* nW1 = (const T*)d_in[15]; const T* nb1 = (const T*)d_in[16];
    const T* nW2 = (const T*)d_in[17]; const T* nb2 = (const T*)d_in[18];
    T* out = (T*)d_out;

    k_dec1<T><<<NGR, 256, 0, stream>>>(dtf, emb, Wg1, bg1, hb);
    k_dec2<T><<<G2D / 64, 256, 0, stream>>>(dtf, hb, Wg2, bg2, nA);

    if (PERM) k_eaperm<T><<<NE / 256, 256, 0, stream>>>(dtf, csr, ea, (unsigned short*)eaP);

    gemm_node<T, 2, 0, 4, false, false><<<GEMM_BLKS, 256, 0, stream>>>(dtf, nA, nullptr, mW0, nullptr, nB);
    k_agg<T, PERM><<<NN / 4, 256, 0, stream>>>(dtf, csr, ptr, nB, ea, eaP, mW0, mb0, nG);
    gemm_node<T, 2, 2, 4, true, true><<<GEMM_BLKS, 256, 0, stream>>>(dtf, nA, nG, uW0, ub0, nB);

    gemm_node<T, 2, 0, 4, false, false><<<GEMM_BLKS, 256, 0, stream>>>(dtf, nB, nullptr, mW1, nullptr, nA);
    k_agg<T, PERM><<<NN / 4, 256, 0, stream>>>(dtf, csr, ptr, nA, ea, eaP, mW1, mb1, nG);
    gemm_node<T, 2, 2, 4, true, true><<<GEMM_BLKS, 256, 0, stream>>>(dtf, nB, nG, uW1, ub1, nA);

    k_mlp_out<T><<<GEMM_BLKS, 256, 0, stream>>>(dtf, nA, nW1, nb1, nW2, nb2, out);
}

extern "C" void kernel_launch(void* const* d_in, const int* in_sizes, int n_in,
                              void* d_out, int out_size, void* d_ws, size_t ws_size,
                              hipStream_t stream) {
    const int* eix = (const int*)d_in[1];

    // workspace carve-up: base ~52.3 MB + optional eaP 51.2 MB
    char* w = (char*)d_ws;
    size_t off = 0;
    auto carve = [&](size_t bytes) { char* p = w + off; off = (off + bytes + 255) & ~(size_t)255; return p; };
    unsigned short* nA = (unsigned short*)carve((size_t)NN * DD * 2);   // 12.8 MB
    unsigned short* nB = (unsigned short*)carve((size_t)NN * DD * 2);   // 12.8 MB
    unsigned short* nG = (unsigned short*)carve((size_t)NN * DD * 2);   // 12.8 MB
    int2* csr = (int2*)carve((size_t)NE * 8);                           // 12.8 MB
    unsigned short* hb = (unsigned short*)carve((size_t)NGR * G1D * 2); // 0.1 MB
    int* deg  = (int*)carve((size_t)NN * 4);
    int* ptr  = (int*)carve((size_t)(NN + 1) * 4);
    int* cur  = (int*)carve((size_t)NN * 4);
    int* bsum = (int*)carve((size_t)256 * 4);
    int* dtf  = (int*)carve(256);
    size_t base_off = off;
    unsigned short* eaP = (unsigned short*)carve((size_t)NE * ECH * 2); // 51.2 MB
    bool perm = (off <= ws_size);           // host-constant branch: graph-safe
    if (!perm) eaP = nullptr, off = base_off;
    (void)in_sizes; (void)n_in; (void)out_size;

    const int SCAN_BLKS = (NN + 511) / 512;   // 196
    const int GEMM_BLKS = (NN / 16 + 3) / 4;  // 1563

    k_detect<<<1, 64, 0, stream>>>((const unsigned short*)d_in[0], eix, dtf);

    // CSR build (dtype-independent)
    k_zero<<<(NN + 255) / 256, 256, 0, stream>>>(deg);
    k_hist<<<NE / 256, 256, 0, stream>>>(eix, dtf, deg);
    k_scan1<<<SCAN_BLKS, 256, 0, stream>>>(deg, bsum);
    k_scan2<<<1, 256, 0, stream>>>(bsum, SCAN_BLKS);
    k_scan3<<<SCAN_BLKS, 256, 0, stream>>>(deg, bsum, ptr, cur);
    k_fill<<<NE / 256, 256, 0, stream>>>(eix, dtf, cur, csr);

    // launch both dtype variants; the wrong one early-exits on dtf[0]
    if (perm) {
        launch_typed<float, true>(d_in, d_out, stream, dtf, csr, ptr, eaP, nA, nB, nG, hb, GEMM_BLKS);
        launch_typed<unsigned short, true>(d_in, d_out, stream, dtf, csr, ptr, eaP, nA, nB, nG, hb, GEMM_BLKS);
    } else {
        launch_typed<float, false>(d_in, d_out, stream, dtf, csr, ptr, nullptr, nA, nB, nG, hb, GEMM_BLKS);
        launch_typed<unsigned short, false>(d_in, d_out, stream, dtf, csr, ptr, nullptr, nA, nB, nG, hb, GEMM_BLKS);
    }
}